// Round 16
// baseline (100.201 us; speedup 1.0000x reference)
//
#include <hip/hip_runtime.h>

// StructuredMAPLoss: B=1024 rows, C=128 classes.
// out[0] = loss (mean over classes), out[1 + i*C + c] = ranking[i][c].
// ONE WAVE PER CLASS (E=16 elements/lane). TPB=512 -> 8 classes/block, grid=16.
// Bitonic sort: j<=8 in-register, j=16..512 shfl_xor (lane dist 1..32).
// Wave-private 2048-bin r-histogram (bank-permuted), wave-only scans.
// ZERO __syncthreads: waves never couple; same-wave DS ops are FIFO-ordered.

constexpr int Bn = 1024;
constexpr int Cn = 128;
constexpr int TPB = 512;
constexpr int WPB = TPB / 64;      // 8 waves (classes) per block
constexpr int E = 16;              // elements per lane
constexpr int NBINS = 2048;
constexpr int ROFF = 3072;         // bin = (r + ROFF) >> 1 ; valid r in [-3071, 1023]

// bank-permuted histogram index: lane l's scan slice (bins l*32..l*32+31)
// lands at s = q*64 + l  -> bank l%32, 2-way aliasing = free.
__device__ __forceinline__ int hswz(int b) { return ((b & 31) << 6) | (b >> 5); }

__device__ __forceinline__ unsigned long long pk3(int ff) {
    return (ff != 0 ? 1ull : 0ull) + (ff == 2 ? (1ull << 21) : 0ull) + (ff == 1 ? (1ull << 42) : 0ull);
}

__global__ __launch_bounds__(TPB) void map_loss_kernel(
    const float* __restrict__ x,
    const int* __restrict__ tgt,
    const void* __restrict__ maskraw,
    float* __restrict__ out)
{
    __shared__ unsigned int hist[WPB][NBINS];        // 64 KB, wave-private slices

    const int tid  = threadIdx.x;
    const int lane = tid & 63;
    const int wid  = tid >> 6;
    const int c    = blockIdx.x * WPB + wid;         // this wave's class

    // ---- mask storage sniff (per-thread, wave-uniform, no barrier) ----
    int mode;
    {
        const int*   wi = (const int*)maskraw;
        const float* wf = (const float*)maskraw;
        bool okInt = true, okF = true;
        #pragma unroll 4
        for (int k = 0; k < 32; ++k) {
            int v = wi[k];
            if (v != 0 && v != 1) okInt = false;
            float fv = wf[k];
            if (fv != 0.0f && fv != 1.0f) okF = false;
        }
        mode = okInt ? 0 : (okF ? 1 : 2);
    }

    // ---- load 16 elements / lane; classify ----
    float xv[E]; int f[E];
    #pragma unroll
    for (int e = 0; e < E; ++e) {
        const int i = lane * E + e;
        const int g = i * Cn + c;
        xv[e] = x[g];
        int t = tgt[g];
        bool m;
        if (mode == 0)      m = ((const int*)maskraw)[g] != 0;
        else if (mode == 1) m = ((const float*)maskraw)[g] != 0.0f;
        else                m = ((const unsigned char*)maskraw)[g] != 0;
        f[e] = m ? ((t == 1) ? 1 : ((t == 0) ? 2 : 3)) : 0;
    }

    // ---- zero this wave's histogram (32 entries/lane, bank-free) ----
    #pragma unroll
    for (int q = 0; q < 32; ++q) hist[wid][q * 64 + lane] = 0u;

    // ---- packed (valid,neg,pos) wave prefix scan ----
    unsigned long long local = 0;
    #pragma unroll
    for (int e = 0; e < E; ++e) local += pk3(f[e]);
    unsigned long long v = local;
    #pragma unroll
    for (int off = 1; off < 64; off <<= 1) {
        unsigned long long o = __shfl_up(v, off);
        if (lane >= off) v += o;
    }
    const unsigned long long tot = __shfl(v, 63);
    unsigned long long run = v - local;              // exclusive prefix at i = lane*E

    const int M = (int)(tot & 0x1FFFFF);
    const int N = (int)((tot >> 21) & 0x1FFFFF);
    const int P = (int)((tot >> 42) & 0x1FFFFF);
    const bool active = (P > 0) && (N > 0);

    // ---- r closed form, ranking write, histogram atomics, 32-bit keys ----
    int r[E];
    unsigned int kr[E];
    #pragma unroll
    for (int e = 0; e < E; ++e) {
        const int i = lane * E + e;
        const int vb = (int)(run & 0x1FFFFF);
        const int nb = (int)((run >> 21) & 0x1FFFFF);
        const int pb = (int)((run >> 42) & 0x1FFFFF);
        const int mfi = (f[e] != 0) ? 1 : 0;
        const int bse = M - mfi - 2 * vb;
        r[e] = (f[e] == 1) ? bse + 2 * nb
             : ((f[e] == 2) ? bse + 2 * pb - 2 * P : bse);
        run += pk3(f[e]);

        out[1 + i * Cn + c] = (active && f[e] != 0) ? (float)r[e] : 0.0f;

        if (f[e] == 1)      atomicAdd(&hist[wid][hswz((r[e] + ROFF) >> 1)], 1u << 16);
        else if (f[e] == 2) atomicAdd(&hist[wid][hswz((r[e] + ROFF) >> 1)], 1u);

        unsigned int bits = __float_as_uint(xv[e]);
        unsigned int masc = bits ^ ((bits >> 31) ? 0xFFFFFFFFu : 0x80000000u);
        unsigned int kw = ~masc;                     // descending-x sorts first
        kr[e] = (f[e] == 0) ? 0xFFFFFFFCu
                            : ((kw & 0xFFFFFFFCu) | (unsigned int)f[e]);
    }

    // ---- bitonic sort (ascending): j<=8 in-reg, j=16..512 shfl_xor ----
    #pragma unroll
    for (int k = 2; k <= Bn; k <<= 1) {
        #pragma unroll
        for (int j = k >> 1; j > 0; j >>= 1) {
            if (j >= E) {                            // lane distance 1..32
                const int jl = j >> 4;
                #pragma unroll
                for (int e = 0; e < E; ++e) {
                    unsigned int o = __shfl_xor(kr[e], jl);
                    const int i = lane * E + e;
                    bool keepmin = ((i & k) == 0) == ((i & j) == 0);
                    kr[e] = ((kr[e] < o) == keepmin) ? kr[e] : o;
                }
            } else {                                 // j in {1,2,4,8}: within lane
                #pragma unroll
                for (int e = 0; e < E; ++e) {
                    if ((e & j) == 0) {
                        const int e2 = e | j;
                        bool up = (((lane * E + e) & k) == 0);
                        unsigned int a = kr[e], b = kr[e2];
                        bool sw = ((a > b) == up);
                        kr[e]  = sw ? b : a;
                        kr[e2] = sw ? a : b;
                    }
                }
            }
        }
    }
    // kr[e] = key at sorted position i = lane*E+e (valids desc-x first, invalids last)

    // ---- histogram inclusive scan (32 bins/lane, wave-only) ----
    unsigned int h[32]; unsigned int hl = 0;
    #pragma unroll
    for (int q = 0; q < 32; ++q) { h[q] = hist[wid][q * 64 + lane]; hl += h[q]; }
    unsigned int hv = hl;
    #pragma unroll
    for (int off = 1; off < 64; off <<= 1) {
        unsigned int o = __shfl_up(hv, off);
        if (lane >= off) hv += o;
    }
    unsigned int hrun = hv - hl;
    #pragma unroll
    for (int q = 0; q < 32; ++q) { hrun += h[q]; hist[wid][q * 64 + lane] = hrun; }

    // ---- AP: pos-indicator prefix over sorted order (wave-only) ----
    int pl = 0;
    #pragma unroll
    for (int e = 0; e < E; ++e) pl += ((kr[e] & 3u) == 1u) ? 1 : 0;
    int pv = pl;
    #pragma unroll
    for (int off = 1; off < 64; off <<= 1) {
        int o = __shfl_up(pv, off);
        if (lane >= off) pv += o;
    }
    float S_ap = 0.0f;
    int prun = pv - pl;
    #pragma unroll
    for (int e = 0; e < E; ++e) {
        int pe = ((kr[e] & 3u) == 1u) ? 1 : 0;
        prun += pe;
        if (pe) S_ap += (float)prun / (float)(lane * E + e + 1);
    }

    // ---- per-element pairwise terms via histogram lookup ----
    float S_t1 = 0.0f, S_t2 = 0.0f, S_px = 0.0f, S_nx = 0.0f;
    #pragma unroll
    for (int e = 0; e < E; ++e) {
        if (f[e] == 1) {
            int B = ((r[e] + ROFF) >> 1) - 1;        // bin >= 1024, B safe
            int cnt = (int)(hist[wid][hswz(B)] & 0xFFFFu);   // negs with r' < r
            S_t1 += xv[e] * (2.0f * (float)cnt - (float)N);
            S_px += xv[e];
        } else if (f[e] == 2) {
            int B = (r[e] + ROFF) >> 1;
            int cnt = P - (int)(hist[wid][hswz(B)] >> 16);   // pos with r' > r
            S_t2 += xv[e] * (2.0f * (float)cnt - (float)P);
            S_nx += xv[e];
        }
    }

    // ---- wave reduction + atomic epilogue (one wave = whole class) ----
    #pragma unroll
    for (int off = 32; off > 0; off >>= 1) {
        S_ap += __shfl_down(S_ap, off);
        S_t1 += __shfl_down(S_t1, off);
        S_t2 += __shfl_down(S_t2, off);
        S_px += __shfl_down(S_px, off);
        S_nx += __shfl_down(S_nx, off);
    }
    if (lane == 0 && active) {
        float Pf = (float)P, Nf = (float)N;
        float denom = Pf * Nf + 1e-8f;
        float contrib = 1.0f
                      - S_ap / (Pf + 1e-8f)
                      + (S_t1 - S_t2) / denom
                      - (Nf * S_px - Pf * S_nx) / denom;
        atomicAdd(out, contrib * (1.0f / (float)Cn));
    }
}

extern "C" void kernel_launch(void* const* d_in, const int* in_sizes, int n_in,
                              void* d_out, int out_size, void* d_ws, size_t ws_size,
                              hipStream_t stream) {
    const float* x   = (const float*)d_in[0];
    const int*   tgt = (const int*)d_in[1];
    const void*  msk = d_in[2];
    float* out = (float*)d_out;

    hipMemsetAsync(out, 0, sizeof(float), stream);   // zero the loss accumulator
    hipLaunchKernelGGL(map_loss_kernel, dim3(Cn / WPB), dim3(TPB), 0, stream,
                       x, tgt, msk, out);
}

// Round 17
// 89.673 us; speedup vs baseline: 1.1174x; 1.1174x over previous
//
#include <hip/hip_runtime.h>

// StructuredMAPLoss: B=1024 rows, C=128 classes.
// out[0] = loss (mean over classes), out[1 + i*C + c] = ranking[i][c].
// ONE WAVE = ONE BLOCK = ONE CLASS (E=16 elements/lane), grid=128 -> 128 CUs.
// Phase order minimizes live registers (no spill): load/classify/keys ->
// r + ranking + hist atomics -> streaming hist scan -> pairwise lookups
// (xv, r die) -> bitonic sort (kr only) -> AP -> wave reduce.
// Bitonic sort: j<=8 in-register, j=16..512 shfl_xor. ZERO __syncthreads.

constexpr int Bn = 1024;
constexpr int Cn = 128;
constexpr int TPB = 64;
constexpr int E = 16;              // elements per lane
constexpr int NBINS = 2048;
constexpr int ROFF = 3072;         // bin = (r + ROFF) >> 1 ; valid r in [-3071, 1023]

// bank-permuted histogram index: lane l owns bins [32l, 32l+32) stored at
// s = q*64 + l -> bank l%32, 2-way aliasing = free; scan in lane order = bin order.
__device__ __forceinline__ int hswz(int b) { return ((b & 31) << 6) | (b >> 5); }

__device__ __forceinline__ unsigned long long pk3(int ff) {
    return (ff != 0 ? 1ull : 0ull) + (ff == 2 ? (1ull << 21) : 0ull) + (ff == 1 ? (1ull << 42) : 0ull);
}

__global__ __launch_bounds__(TPB) void map_loss_kernel(
    const float* __restrict__ x,
    const int* __restrict__ tgt,
    const void* __restrict__ maskraw,
    float* __restrict__ out)
{
    __shared__ unsigned int hist[NBINS];             // 8 KB, block-private (1 wave)

    const int lane = threadIdx.x;                    // 0..63
    const int c    = blockIdx.x;                     // this wave's class

    // ---- mask storage sniff (wave-uniform, no barrier) ----
    int mode;
    {
        const int*   wi = (const int*)maskraw;
        const float* wf = (const float*)maskraw;
        bool okInt = true, okF = true;
        #pragma unroll 4
        for (int k = 0; k < 32; ++k) {
            int v = wi[k];
            if (v != 0 && v != 1) okInt = false;
            float fv = wf[k];
            if (fv != 0.0f && fv != 1.0f) okF = false;
        }
        mode = okInt ? 0 : (okF ? 1 : 2);
    }

    // ---- zero histogram (32 slots/lane) ----
    #pragma unroll
    for (int q = 0; q < 32; ++q) hist[q * 64 + lane] = 0u;

    // ---- load 16 elements / lane; classify; build 32-bit keys ----
    // f is carried in kr low bits (invalid sentinel 0xFFFFFFFC has low bits 0).
    float xv[E];
    unsigned int kr[E];
    unsigned long long local = 0;
    #pragma unroll
    for (int e = 0; e < E; ++e) {
        const int i = lane * E + e;
        const int g = i * Cn + c;
        xv[e] = x[g];
        int t = tgt[g];
        bool m;
        if (mode == 0)      m = ((const int*)maskraw)[g] != 0;
        else if (mode == 1) m = ((const float*)maskraw)[g] != 0.0f;
        else                m = ((const unsigned char*)maskraw)[g] != 0;
        int fe = m ? ((t == 1) ? 1 : ((t == 0) ? 2 : 3)) : 0;
        local += pk3(fe);

        unsigned int bits = __float_as_uint(xv[e]);
        unsigned int masc = bits ^ ((bits >> 31) ? 0xFFFFFFFFu : 0x80000000u);
        unsigned int kw = ~masc;                     // descending-x sorts first
        kr[e] = (fe == 0) ? 0xFFFFFFFCu
                          : ((kw & 0xFFFFFFFCu) | (unsigned int)fe);
    }

    // ---- packed (valid,neg,pos) wave prefix scan ----
    unsigned long long v = local;
    #pragma unroll
    for (int off = 1; off < 64; off <<= 1) {
        unsigned long long o = __shfl_up(v, off);
        if (lane >= off) v += o;
    }
    const unsigned long long tot = __shfl(v, 63);
    unsigned long long run = v - local;              // exclusive prefix at i = lane*E

    const int M = (int)(tot & 0x1FFFFF);
    const int N = (int)((tot >> 21) & 0x1FFFFF);
    const int P = (int)((tot >> 42) & 0x1FFFFF);
    const bool active = (P > 0) && (N > 0);

    // ---- r closed form, ranking write, histogram atomics ----
    int r[E];
    #pragma unroll
    for (int e = 0; e < E; ++e) {
        const int i = lane * E + e;
        const int fe = (int)(kr[e] & 3u);
        const int vb = (int)(run & 0x1FFFFF);
        const int nb = (int)((run >> 21) & 0x1FFFFF);
        const int pb = (int)((run >> 42) & 0x1FFFFF);
        const int bse = M - ((fe != 0) ? 1 : 0) - 2 * vb;
        r[e] = (fe == 1) ? bse + 2 * nb
             : ((fe == 2) ? bse + 2 * pb - 2 * P : bse);
        run += pk3(fe);

        out[1 + i * Cn + c] = (active && fe != 0) ? (float)r[e] : 0.0f;

        if (fe == 1)      atomicAdd(&hist[hswz((r[e] + ROFF) >> 1)], 1u << 16);
        else if (fe == 2) atomicAdd(&hist[hswz((r[e] + ROFF) >> 1)], 1u);
    }

    // ---- streaming histogram inclusive scan (same-wave DS is in-order) ----
    unsigned int hl = 0;
    #pragma unroll
    for (int q = 0; q < 32; ++q) hl += hist[q * 64 + lane];
    unsigned int hv = hl;
    #pragma unroll
    for (int off = 1; off < 64; off <<= 1) {
        unsigned int o = __shfl_up(hv, off);
        if (lane >= off) hv += o;
    }
    unsigned int hrun = hv - hl;
    #pragma unroll
    for (int q = 0; q < 32; ++q) {
        unsigned int hq = hist[q * 64 + lane];
        hrun += hq;
        hist[q * 64 + lane] = hrun;
    }

    // ---- pairwise terms via histogram lookup (xv, r die here) ----
    float S_t1 = 0.0f, S_t2 = 0.0f, S_px = 0.0f, S_nx = 0.0f;
    #pragma unroll
    for (int e = 0; e < E; ++e) {
        const int fe = (int)(kr[e] & 3u);
        if (fe == 1) {
            int B = ((r[e] + ROFF) >> 1) - 1;        // pos bin >= 1024, B safe
            int cnt = (int)(hist[hswz(B)] & 0xFFFFu);        // negs with r' < r
            S_t1 += xv[e] * (2.0f * (float)cnt - (float)N);
            S_px += xv[e];
        } else if (fe == 2) {
            int B = (r[e] + ROFF) >> 1;
            int cnt = P - (int)(hist[hswz(B)] >> 16);        // pos with r' > r
            S_t2 += xv[e] * (2.0f * (float)cnt - (float)P);
            S_nx += xv[e];
        }
    }

    // ---- bitonic sort (ascending): j<=8 in-reg, j=16..512 shfl_xor ----
    #pragma unroll
    for (int k = 2; k <= Bn; k <<= 1) {
        #pragma unroll
        for (int j = k >> 1; j > 0; j >>= 1) {
            if (j >= E) {                            // lane distance 1..32
                const int jl = j >> 4;
                #pragma unroll
                for (int e = 0; e < E; ++e) {
                    unsigned int o = __shfl_xor(kr[e], jl);
                    const int i = lane * E + e;
                    bool keepmin = ((i & k) == 0) == ((i & j) == 0);
                    kr[e] = ((kr[e] < o) == keepmin) ? kr[e] : o;
                }
            } else {                                 // j in {1,2,4,8}: within lane
                #pragma unroll
                for (int e = 0; e < E; ++e) {
                    if ((e & j) == 0) {
                        const int e2 = e | j;
                        bool up = (((lane * E + e) & k) == 0);
                        unsigned int a = kr[e], b = kr[e2];
                        bool sw = ((a > b) == up);
                        kr[e]  = sw ? b : a;
                        kr[e2] = sw ? a : b;
                    }
                }
            }
        }
    }
    // kr[e] = key at sorted position i = lane*E+e (valids desc-x first, invalids last)

    // ---- AP: pos-indicator prefix over sorted order ----
    int pl = 0;
    #pragma unroll
    for (int e = 0; e < E; ++e) pl += ((kr[e] & 3u) == 1u) ? 1 : 0;
    int pv = pl;
    #pragma unroll
    for (int off = 1; off < 64; off <<= 1) {
        int o = __shfl_up(pv, off);
        if (lane >= off) pv += o;
    }
    float S_ap = 0.0f;
    int prun = pv - pl;
    #pragma unroll
    for (int e = 0; e < E; ++e) {
        int pe = ((kr[e] & 3u) == 1u) ? 1 : 0;
        prun += pe;
        if (pe) S_ap += (float)prun / (float)(lane * E + e + 1);
    }

    // ---- wave reduction + atomic epilogue ----
    #pragma unroll
    for (int off = 32; off > 0; off >>= 1) {
        S_ap += __shfl_down(S_ap, off);
        S_t1 += __shfl_down(S_t1, off);
        S_t2 += __shfl_down(S_t2, off);
        S_px += __shfl_down(S_px, off);
        S_nx += __shfl_down(S_nx, off);
    }
    if (lane == 0 && active) {
        float Pf = (float)P, Nf = (float)N;
        float denom = Pf * Nf + 1e-8f;
        float contrib = 1.0f
                      - S_ap / (Pf + 1e-8f)
                      + (S_t1 - S_t2) / denom
                      - (Nf * S_px - Pf * S_nx) / denom;
        atomicAdd(out, contrib * (1.0f / (float)Cn));
    }
}

extern "C" void kernel_launch(void* const* d_in, const int* in_sizes, int n_in,
                              void* d_out, int out_size, void* d_ws, size_t ws_size,
                              hipStream_t stream) {
    const float* x   = (const float*)d_in[0];
    const int*   tgt = (const int*)d_in[1];
    const void*  msk = d_in[2];
    float* out = (float*)d_out;

    hipMemsetAsync(out, 0, sizeof(float), stream);   // zero the loss accumulator
    hipLaunchKernelGGL(map_loss_kernel, dim3(Cn), dim3(TPB), 0, stream,
                       x, tgt, msk, out);
}

// Round 18
// 72.861 us; speedup vs baseline: 1.3752x; 1.2307x over previous
//
#include <hip/hip_runtime.h>

// StructuredMAPLoss: B=1024 rows, C=128 classes.
// out[0] = loss (mean over classes), out[1 + i*C + c] = ranking[i][c].
// One block (512 threads, 2 elements/thread) per class.
// 32-bit sort keys: key = (kw & ~3) | f, invalid -> 0xFFFFFFFC (sorts last).
// Bitonic sort: j==1 in-reg, j=2..64 shfl_xor, j>=128 double-buffered LDS.
// r-histogram (2048 bins) for the pairwise score terms.
// BEST MEASURED (round 11): dur_us 72.5, absmax 0.0.

constexpr int Bn = 1024;
constexpr int Cn = 128;
constexpr int TPB = 512;
constexpr int E = 2;
constexpr int NBINS = 2048;
constexpr int ROFF = 3072;   // bin = (r + ROFF) >> 1 ; valid r in [-3071, 1023]

__device__ __forceinline__ unsigned long long pk3(int ff) {
    return (ff != 0 ? 1ull : 0ull) + (ff == 2 ? (1ull << 21) : 0ull) + (ff == 1 ? (1ull << 42) : 0ull);
}

__global__ __launch_bounds__(TPB) void map_loss_kernel(
    const float* __restrict__ x,
    const int* __restrict__ tgt,
    const void* __restrict__ maskraw,
    float* __restrict__ out)
{
    __shared__ unsigned int kbuf[2][Bn];             // 8 KB (double buffer)
    __shared__ unsigned int hist[NBINS];             // 8 KB
    __shared__ unsigned long long wtot[8];
    __shared__ unsigned int hwt[8];
    __shared__ int iwt[8];
    __shared__ float red[5][8];

    const int c    = blockIdx.x;
    const int tid  = threadIdx.x;
    const int lane = tid & 63;
    const int wid  = tid >> 6;

    // ---- mask storage sniff (redundant per-thread; wave-uniform, no barrier) ----
    int mode;
    {
        const int*   wi = (const int*)maskraw;
        const float* wf = (const float*)maskraw;
        bool okInt = true, okF = true;
        #pragma unroll 4
        for (int k = 0; k < 32; ++k) {
            int v = wi[k];
            if (v != 0 && v != 1) okInt = false;
            float fv = wf[k];
            if (fv != 0.0f && fv != 1.0f) okF = false;
        }
        mode = okInt ? 0 : (okF ? 1 : 2);
    }

    // ---- load 2 elements / thread; classify; zero histogram ----
    float xv[E]; int f[E];
    #pragma unroll
    for (int e = 0; e < E; ++e) {
        const int i = tid * E + e;
        const int g = i * Cn + c;
        xv[e] = x[g];
        int t = tgt[g];
        bool m;
        if (mode == 0)      m = ((const int*)maskraw)[g] != 0;
        else if (mode == 1) m = ((const float*)maskraw)[g] != 0.0f;
        else                m = ((const unsigned char*)maskraw)[g] != 0;
        f[e] = m ? ((t == 1) ? 1 : ((t == 0) ? 2 : 3)) : 0;
    }
    #pragma unroll
    for (int q = 0; q < NBINS / TPB; ++q) hist[tid * (NBINS / TPB) + q] = 0u;

    // ---- packed (valid,neg,pos) prefix scan over element order ----
    unsigned long long local = pk3(f[0]) + pk3(f[1]);
    unsigned long long v = local;
    #pragma unroll
    for (int off = 1; off < 64; off <<= 1) {
        unsigned long long o = __shfl_up(v, off);
        if (lane >= off) v += o;
    }
    if (lane == 63) wtot[wid] = v;
    __syncthreads();                                 // fences wtot + hist zero
    unsigned long long wpre = 0, tot = 0;
    #pragma unroll
    for (int w = 0; w < 8; ++w) {
        unsigned long long t = wtot[w];
        if (w < wid) wpre += t;
        tot += t;
    }
    unsigned long long run = wpre + v - local;       // exclusive prefix at i = tid*E

    const int M = (int)(tot & 0x1FFFFF);
    const int N = (int)((tot >> 21) & 0x1FFFFF);
    const int P = (int)((tot >> 42) & 0x1FFFFF);
    const bool active = (P > 0) && (N > 0);

    // ---- r closed form, ranking write, histogram atomics, 32-bit keys ----
    int r[E];
    unsigned int kr[E];
    #pragma unroll
    for (int e = 0; e < E; ++e) {
        const int i = tid * E + e;
        const int vb = (int)(run & 0x1FFFFF);
        const int nb = (int)((run >> 21) & 0x1FFFFF);
        const int pb = (int)((run >> 42) & 0x1FFFFF);
        const int mfi = (f[e] != 0) ? 1 : 0;
        const int bse = M - mfi - 2 * vb;
        r[e] = (f[e] == 1) ? bse + 2 * nb
             : ((f[e] == 2) ? bse + 2 * pb - 2 * P : bse);
        run += pk3(f[e]);

        out[1 + i * Cn + c] = (active && f[e] != 0) ? (float)r[e] : 0.0f;

        if (f[e] == 1)      atomicAdd(&hist[(r[e] + ROFF) >> 1], 1u << 16);
        else if (f[e] == 2) atomicAdd(&hist[(r[e] + ROFF) >> 1], 1u);

        unsigned int bits = __float_as_uint(xv[e]);
        unsigned int masc = bits ^ ((bits >> 31) ? 0xFFFFFFFFu : 0x80000000u);
        unsigned int kw = ~masc;                     // descending-x sorts first
        kr[e] = (f[e] == 0) ? 0xFFFFFFFCu
                            : ((kw & 0xFFFFFFFCu) | (unsigned int)f[e]);
    }

    // ---- bitonic sort (ascending): j==1 in-reg, j=2..64 shfl, j>=128 LDS ----
    int lb = 0;
    #pragma unroll
    for (int k = 2; k <= Bn; k <<= 1) {
        #pragma unroll
        for (int j = k >> 1; j > 0; j >>= 1) {
            if (j >= 128) {
                *(unsigned long long*)&kbuf[lb][tid * E] =
                    (unsigned long long)kr[0] | ((unsigned long long)kr[1] << 32);
                __syncthreads();                     // 6 of these total
                const int ptid = tid ^ (j >> 1);
                unsigned long long oo = *(const unsigned long long*)&kbuf[lb][ptid * E];
                unsigned int o0 = (unsigned int)oo;
                unsigned int o1 = (unsigned int)(oo >> 32);
                {
                    const int i = tid * E;
                    bool keepmin = ((i & k) == 0) == ((i & j) == 0);
                    kr[0] = ((kr[0] < o0) == keepmin) ? kr[0] : o0;
                    kr[1] = ((kr[1] < o1) == keepmin) ? kr[1] : o1;
                }
                lb ^= 1;                             // WAR safe: next write >=1 barrier away
            } else if (j >= E) {
                const int jl = j >> 1;               // lane distance 1..32
                #pragma unroll
                for (int e = 0; e < E; ++e) {
                    unsigned int o = __shfl_xor(kr[e], jl);
                    const int i = tid * E + e;
                    bool keepmin = ((i & k) == 0) == ((i & j) == 0);
                    kr[e] = ((kr[e] < o) == keepmin) ? kr[e] : o;
                }
            } else {                                 // j == 1: within thread
                const int i0 = tid * E;
                bool up = ((i0 & k) == 0);
                unsigned int a = kr[0], b = kr[1];
                bool sw = ((a > b) == up);
                kr[0] = sw ? b : a;
                kr[1] = sw ? a : b;
            }
        }
    }
    // kr[e] = key at sorted position i = tid*E+e (valids desc-x first, invalids last)

    // ---- histogram inclusive scan (4 bins/thread) + AP pos-indicator scan ----
    unsigned int h[NBINS / TPB]; unsigned int hl = 0;
    #pragma unroll
    for (int q = 0; q < NBINS / TPB; ++q) { h[q] = hist[tid * (NBINS / TPB) + q]; hl += h[q]; }
    unsigned int hv = hl;
    #pragma unroll
    for (int off = 1; off < 64; off <<= 1) {
        unsigned int o = __shfl_up(hv, off);
        if (lane >= off) hv += o;
    }
    if (lane == 63) hwt[wid] = hv;

    int ps[E]; int pl = 0;
    #pragma unroll
    for (int e = 0; e < E; ++e) { ps[e] = ((kr[e] & 3u) == 1u) ? 1 : 0; pl += ps[e]; }
    int pv = pl;
    #pragma unroll
    for (int off = 1; off < 64; off <<= 1) {
        int o = __shfl_up(pv, off);
        if (lane >= off) pv += o;
    }
    if (lane == 63) iwt[wid] = pv;
    __syncthreads();                                 // hwt + iwt ready

    unsigned int hpre = 0; int ppre = 0;
    #pragma unroll
    for (int w = 0; w < 8; ++w) {
        if (w < wid) { hpre += hwt[w]; ppre += iwt[w]; }
    }
    unsigned int hrun = hpre + hv - hl;
    #pragma unroll
    for (int q = 0; q < NBINS / TPB; ++q) { hrun += h[q]; hist[tid * (NBINS / TPB) + q] = hrun; }

    float S_ap = 0.0f;
    int prun = ppre + pv - pl;
    #pragma unroll
    for (int e = 0; e < E; ++e) {
        prun += ps[e];
        if (ps[e]) S_ap += (float)prun / (float)(tid * E + e + 1);
    }
    __syncthreads();                                 // inclusive hist visible

    // ---- per-element pairwise terms via histogram lookup ----
    float S_t1 = 0.0f, S_t2 = 0.0f, S_px = 0.0f, S_nx = 0.0f;
    #pragma unroll
    for (int e = 0; e < E; ++e) {
        if (f[e] == 1) {
            int rb = (r[e] + ROFF) >> 1;             // >= 1024, rb-1 safe
            int cnt = (int)(hist[rb - 1] & 0xFFFFu); // negs with r' < r
            S_t1 += xv[e] * (2.0f * (float)cnt - (float)N);
            S_px += xv[e];
        } else if (f[e] == 2) {
            int rb = (r[e] + ROFF) >> 1;
            int cnt = P - (int)(hist[rb] >> 16);     // pos with r' > r
            S_t2 += xv[e] * (2.0f * (float)cnt - (float)P);
            S_nx += xv[e];
        }
    }

    // ---- block reduction of 5 partial sums ----
    #pragma unroll
    for (int off = 32; off > 0; off >>= 1) {
        S_ap += __shfl_down(S_ap, off);
        S_t1 += __shfl_down(S_t1, off);
        S_t2 += __shfl_down(S_t2, off);
        S_px += __shfl_down(S_px, off);
        S_nx += __shfl_down(S_nx, off);
    }
    if (lane == 0) {
        red[0][wid] = S_ap; red[1][wid] = S_t1; red[2][wid] = S_t2;
        red[3][wid] = S_px; red[4][wid] = S_nx;
    }
    __syncthreads();
    if (tid == 0) {
        float apS = 0.f, t1 = 0.f, t2 = 0.f, px = 0.f, nx = 0.f;
        #pragma unroll
        for (int w = 0; w < 8; ++w) {
            apS += red[0][w]; t1 += red[1][w]; t2 += red[2][w];
            px  += red[3][w]; nx += red[4][w];
        }
        float contrib = 0.0f;
        if (active) {
            float Pf = (float)P, Nf = (float)N;
            float denom = Pf * Nf + 1e-8f;
            contrib = 1.0f
                    - apS / (Pf + 1e-8f)
                    + (t1 - t2) / denom
                    - (Nf * px - Pf * nx) / denom;
        }
        atomicAdd(out, contrib * (1.0f / (float)Cn));
    }
}

extern "C" void kernel_launch(void* const* d_in, const int* in_sizes, int n_in,
                              void* d_out, int out_size, void* d_ws, size_t ws_size,
                              hipStream_t stream) {
    const float* x   = (const float*)d_in[0];
    const int*   tgt = (const int*)d_in[1];
    const void*  msk = d_in[2];
    float* out = (float*)d_out;

    hipMemsetAsync(out, 0, sizeof(float), stream);   // zero the loss accumulator
    hipLaunchKernelGGL(map_loss_kernel, dim3(Cn), dim3(TPB), 0, stream,
                       x, tgt, msk, out);
}